// Round 2
// baseline (1402.756 us; speedup 1.0000x reference)
//
#include <hip/hip_runtime.h>
#include <hip/hip_bf16.h>

static constexpr int NF   = 50;   // input features
static constexpr int C1   = 64;   // conv1/conv2 channels
static constexpr int OUTF = 16;   // final output features
static constexpr int SCAN_T = 256;
static constexpr int SCAN_I = 4;

// ---------------------------------------------------------------- CSR build
__global__ void deg_count_kernel(const int* __restrict__ row, const float* __restrict__ w,
                                 float* __restrict__ deg, int* __restrict__ cnt, int e)
{
    int i = blockIdx.x * blockDim.x + threadIdx.x;
    if (i < e) {
        int r = row[i];
        atomicAdd(&deg[r], w[i]);
        atomicAdd(&cnt[r], 1);
    }
}

__global__ void dis_kernel(float* __restrict__ deg, int n)
{
    int i = blockIdx.x * blockDim.x + threadIdx.x;
    if (i < n) {
        float d = deg[i];
        deg[i] = (d > 0.f) ? (1.f / sqrtf(d)) : 0.f;   // deg buffer becomes dis
    }
}

__global__ void scan_partial(const int* __restrict__ cnt, int* __restrict__ bsum, int n)
{
    __shared__ int sm[SCAN_T];
    int t = threadIdx.x;
    int base = blockIdx.x * SCAN_T * SCAN_I + t * SCAN_I;
    int s = 0;
    #pragma unroll
    for (int k = 0; k < SCAN_I; ++k) { int i = base + k; if (i < n) s += cnt[i]; }
    sm[t] = s; __syncthreads();
    for (int off = SCAN_T / 2; off > 0; off >>= 1) {
        if (t < off) sm[t] += sm[t + off];
        __syncthreads();
    }
    if (t == 0) bsum[blockIdx.x] = sm[0];
}

// single block; requires nb <= 256 (here nb = 98)
__global__ void scan_bsums(int* __restrict__ bsum, int nb)
{
    __shared__ int sm[256];
    int t = threadIdx.x;
    sm[t] = (t < nb) ? bsum[t] : 0;
    __syncthreads();
    for (int off = 1; off < 256; off <<= 1) {
        int v = (t >= off) ? sm[t - off] : 0;
        __syncthreads();
        sm[t] += v;
        __syncthreads();
    }
    if (t < nb) bsum[t] = (t == 0) ? 0 : sm[t - 1];   // exclusive
}

__global__ void scan_final(const int* __restrict__ cnt, const int* __restrict__ bsum,
                           int* __restrict__ rowptr, int n)
{
    __shared__ int sm[SCAN_T];
    int t = threadIdx.x;
    int base = blockIdx.x * SCAN_T * SCAN_I + t * SCAN_I;
    int v[SCAN_I]; int s = 0;
    #pragma unroll
    for (int k = 0; k < SCAN_I; ++k) { int i = base + k; v[k] = (i < n) ? cnt[i] : 0; s += v[k]; }
    sm[t] = s; __syncthreads();
    for (int off = 1; off < SCAN_T; off <<= 1) {
        int x = (t >= off) ? sm[t - off] : 0;
        __syncthreads();
        sm[t] += x;
        __syncthreads();
    }
    int pref = bsum[blockIdx.x] + sm[t] - s;   // thread-exclusive prefix
    #pragma unroll
    for (int k = 0; k < SCAN_I; ++k) {
        int i = base + k;
        if (i < n) { rowptr[i] = pref; pref += v[k]; }
    }
}

__global__ void scatter_kernel(const int* __restrict__ row, const int* __restrict__ col,
                               const float* __restrict__ w, const float* __restrict__ dis,
                               const int* __restrict__ rowptr, int* __restrict__ fill,
                               int* __restrict__ col_s, float* __restrict__ norm_s, int e)
{
    int i = blockIdx.x * blockDim.x + threadIdx.x;
    if (i < e) {
        int r = row[i], c = col[i];
        int pos = rowptr[r] + atomicAdd(&fill[r], 1);
        col_s[pos]  = c;
        norm_s[pos] = -dis[r] * w[i] * dis[c];
    }
}

// ---------------------------------------------------------------- propagate
// one wave per row; lane = feature; gather-only, no atomics
template<int F>
__global__ void prop_kernel(const float* __restrict__ xin, int xstride,
                            const int* __restrict__ rowptr, const int* __restrict__ cnt,
                            const int* __restrict__ col_s, const float* __restrict__ norm_s,
                            float* __restrict__ yout, int n)
{
    int gw = (blockIdx.x * blockDim.x + threadIdx.x) >> 6;
    int lane = threadIdx.x & 63;
    if (gw >= n) return;
    int st = rowptr[gw], m = cnt[gw];
    float acc = 0.f;
    for (int t = 0; t < m; ++t) {
        int c   = col_s[st + t];
        float nv = norm_s[st + t];
        if (F == 64 || lane < F) acc += nv * xin[c * xstride + lane];
    }
    if (F == 64 || lane < F) yout[gw * C1 + lane] = acc;
}

// ---------------------------------------------------------------- conv1 combine (+BN stats)
// h = relu(x@W0 + P1@W1 + (2*prop(P1) - x)@W2 + b1); prop(P1) computed inline.
__global__ __launch_bounds__(512) void combine1_kernel(
    const float* __restrict__ x, const float* __restrict__ P1,
    const int* __restrict__ rowptr, const int* __restrict__ cnt,
    const int* __restrict__ col_s, const float* __restrict__ norm_s,
    const float* __restrict__ W1, const float* __restrict__ b1,
    float* __restrict__ h, float* __restrict__ stats, int n)
{
    __shared__ float WL[3 * NF * C1];     // 38400 B
    __shared__ float red[2][8][64];       // 4 KB
    for (int i = threadIdx.x; i < 3 * NF * C1; i += blockDim.x) WL[i] = W1[i];
    __syncthreads();

    const int lane = threadIdx.x & 63;
    const int wv   = threadIdx.x >> 6;
    const int gw   = blockIdx.x * 8 + wv;
    const int rstep = gridDim.x * 8 * 4;
    const float bias = b1[lane];
    float ssum = 0.f, ssq = 0.f;

    for (int r0 = gw * 4; r0 < n; r0 += rstep) {
        const int nr = min(4, n - r0);
        // inline prop(P1): lane = feature (lanes >= 50 compute garbage, never used)
        float s[4] = {0.f, 0.f, 0.f, 0.f};
        #pragma unroll
        for (int r = 0; r < 4; ++r) {
            if (r < nr) {
                int st = rowptr[r0 + r], m = cnt[r0 + r];
                float a = 0.f;
                for (int t = 0; t < m; ++t) {
                    int c = col_s[st + t];
                    float nv = norm_s[st + t];
                    a += nv * P1[c * C1 + lane];   // stride-64 rows: in-bounds for all lanes
                }
                s[r] = a;
            }
        }
        int rr[4];
        #pragma unroll
        for (int r = 0; r < 4; ++r) rr[r] = (r < nr) ? (r0 + r) : r0;   // clamp for safe loads

        float acc[4] = {bias, bias, bias, bias};
        for (int f = 0; f < NF; ++f) {
            float w0 = WL[f * C1 + lane];
            float w1 = WL[(NF + f) * C1 + lane];
            float w2 = WL[(2 * NF + f) * C1 + lane];
            #pragma unroll
            for (int r = 0; r < 4; ++r) {
                float t0 = x[rr[r] * NF + f];          // wave-broadcast load
                float t1 = P1[rr[r] * C1 + f];
                float t2 = 2.f * __shfl(s[r], f) - t0;
                acc[r] += t0 * w0 + t1 * w1 + t2 * w2;
            }
        }
        #pragma unroll
        for (int r = 0; r < 4; ++r) {
            if (r < nr) {
                float v = fmaxf(acc[r], 0.f);
                h[(r0 + r) * C1 + lane] = v;
                ssum += v; ssq += v * v;
            }
        }
    }
    red[0][wv][lane] = ssum;
    red[1][wv][lane] = ssq;
    __syncthreads();
    int t = threadIdx.x;
    if (t < 128) {
        int which = t >> 6, j = t & 63;
        float tot = 0.f;
        #pragma unroll
        for (int wq = 0; wq < 8; ++wq) tot += red[which][wq][j];
        atomicAdd(&stats[which * 64 + j], tot);
    }
}

// ---------------------------------------------------------------- batch norm
__global__ void bn_finalize_kernel(float* __restrict__ stats, const float* __restrict__ gamma,
                                   const float* __restrict__ beta, float inv_n)
{
    int j = threadIdx.x;
    if (j < 64) {
        float mu   = stats[j] * inv_n;
        float var  = stats[64 + j] * inv_n - mu * mu;
        float rstd = 1.f / sqrtf(var + 1e-5f);
        float sc   = gamma[j] * rstd;
        stats[128 + j] = sc;
        stats[192 + j] = beta[j] - mu * sc;
    }
}

__global__ void bn_apply_kernel(float* __restrict__ h, const float* __restrict__ stats, int n4)
{
    int i = blockIdx.x * blockDim.x + threadIdx.x;
    const int stride = gridDim.x * blockDim.x;      // multiple of 16 -> j0 invariant
    int j0 = (i * 4) & 63;
    float s0 = stats[128 + j0], s1 = stats[129 + j0], s2 = stats[130 + j0], s3 = stats[131 + j0];
    float b0 = stats[192 + j0], b1 = stats[193 + j0], b2 = stats[194 + j0], b3 = stats[195 + j0];
    float4* h4 = (float4*)h;
    for (; i < n4; i += stride) {
        float4 v = h4[i];
        v.x = v.x * s0 + b0;
        v.y = v.y * s1 + b1;
        v.z = v.z * s2 + b2;
        v.w = v.w * s3 + b3;
        h4[i] = v;
    }
}

// ---------------------------------------------------------------- conv2 combine + final linear
// g = relu(hb@W0 + Q1@W1 + (2*prop(Q1) - hb)@W2 + b2);  out = g @ linW^T + linb
__global__ __launch_bounds__(512) void combine2_kernel(
    const float* __restrict__ hb, const float* __restrict__ Q1,
    const int* __restrict__ rowptr, const int* __restrict__ cnt,
    const int* __restrict__ col_s, const float* __restrict__ norm_s,
    const float* __restrict__ W2, const float* __restrict__ b2,
    const float* __restrict__ linW, const float* __restrict__ linb,
    float* __restrict__ out, int n)
{
    __shared__ float WL[3 * C1 * C1];     // 48 KB
    __shared__ float LWT[C1 * OUTF];      // linW transposed [j][o], 4 KB
    __shared__ float gbuf[8][4][C1];      // 8 KB, per-wave staging for final linear
    for (int i = threadIdx.x; i < 3 * C1 * C1; i += blockDim.x) WL[i] = W2[i];
    for (int i = threadIdx.x; i < C1 * OUTF; i += blockDim.x) {
        int j = i / OUTF, o = i % OUTF;
        LWT[i] = linW[o * C1 + j];
    }
    __syncthreads();

    const int lane = threadIdx.x & 63;
    const int wv   = threadIdx.x >> 6;
    const int gw   = blockIdx.x * 8 + wv;
    const int rstep = gridDim.x * 8 * 4;
    const float bias = b2[lane];
    const float lb   = linb[lane & 15];
    const int rsel = lane >> 4, osel = lane & 15;

    for (int r0 = gw * 4; r0 < n; r0 += rstep) {
        const int nr = min(4, n - r0);
        float s[4] = {0.f, 0.f, 0.f, 0.f};
        #pragma unroll
        for (int r = 0; r < 4; ++r) {
            if (r < nr) {
                int st = rowptr[r0 + r], m = cnt[r0 + r];
                float a = 0.f;
                for (int t = 0; t < m; ++t) {
                    int c = col_s[st + t];
                    float nv = norm_s[st + t];
                    a += nv * Q1[c * C1 + lane];
                }
                s[r] = a;
            }
        }
        int rr[4];
        #pragma unroll
        for (int r = 0; r < 4; ++r) rr[r] = (r < nr) ? (r0 + r) : r0;

        float acc[4] = {bias, bias, bias, bias};
        for (int f = 0; f < C1; ++f) {
            float w0 = WL[f * C1 + lane];
            float w1 = WL[(C1 + f) * C1 + lane];
            float w2 = WL[(2 * C1 + f) * C1 + lane];
            #pragma unroll
            for (int r = 0; r < 4; ++r) {
                float t0 = hb[rr[r] * C1 + f];
                float t1 = Q1[rr[r] * C1 + f];
                float t2 = 2.f * __shfl(s[r], f) - t0;
                acc[r] += t0 * w0 + t1 * w1 + t2 * w2;
            }
        }
        // stage relu'd g for this wave's 4 rows, then 64 lanes cover 4 rows x 16 outs
        #pragma unroll
        for (int r = 0; r < 4; ++r)
            gbuf[wv][r][lane] = (r < nr) ? fmaxf(acc[r], 0.f) : 0.f;
        // same-wave LDS write->read: DS pipe is in-order per wave on CDNA
        float oa = lb;
        for (int j = 0; j < C1; ++j)
            oa += gbuf[wv][rsel][j] * LWT[j * OUTF + osel];
        int rw = r0 + rsel;
        if (rw < n) out[rw * OUTF + osel] = oa;   // contiguous 256B store per wave
    }
}

// ---------------------------------------------------------------- launch
extern "C" void kernel_launch(void* const* d_in, const int* in_sizes, int n_in,
                              void* d_out, int out_size, void* d_ws, size_t ws_size,
                              hipStream_t stream)
{
    const float* x     = (const float*)d_in[0];
    const int*   ei    = (const int*)  d_in[1];
    const float* ew    = (const float*)d_in[2];
    const float* W1    = (const float*)d_in[3];
    const float* b1    = (const float*)d_in[4];
    const float* W2    = (const float*)d_in[5];
    const float* b2    = (const float*)d_in[6];
    const float* gamma = (const float*)d_in[7];
    const float* beta  = (const float*)d_in[8];
    const float* linW  = (const float*)d_in[9];
    const float* linb  = (const float*)d_in[10];
    float* out = (float*)d_out;
    (void)n_in; (void)out_size; (void)ws_size;

    const int n = in_sizes[0] / NF;    // 100000
    const int e = in_sizes[2];         // 1600000
    const int* row = ei;
    const int* col = ei + e;

    char* ws = (char*)d_ws;
    size_t off = 0;
    auto alloc = [&](size_t bytes) -> void* {
        void* p = ws + off;
        off += (bytes + 255) & ~(size_t)255;
        return p;
    };
    float* deg    = (float*)alloc((size_t)n * 4);   // becomes dis in-place
    int*   cnt    = (int*)  alloc((size_t)n * 4);
    int*   rowptr = (int*)  alloc((size_t)n * 4);
    int*   fill   = (int*)  alloc((size_t)n * 4);
    int*   bsum   = (int*)  alloc(256 * 4);
    float* stats  = (float*)alloc(256 * 4);         // [sum|sumsq|scale|shift] x 64
    int*   col_s  = (int*)  alloc((size_t)e * 4);
    float* norm_s = (float*)alloc((size_t)e * 4);
    float* U      = (float*)alloc((size_t)n * C1 * 4);   // P1, then Q1
    float* H      = (float*)alloc((size_t)n * C1 * 4);   // h, BN in-place

    hipMemsetAsync(deg,   0, (size_t)n * 4, stream);
    hipMemsetAsync(cnt,   0, (size_t)n * 4, stream);
    hipMemsetAsync(fill,  0, (size_t)n * 4, stream);
    hipMemsetAsync(stats, 0, 256 * 4, stream);

    const int eb  = (e + 255) / 256;
    const int nbk = (n + 255) / 256;
    deg_count_kernel<<<eb, 256, 0, stream>>>(row, ew, deg, cnt, e);
    dis_kernel<<<nbk, 256, 0, stream>>>(deg, n);

    const int nb = (n + SCAN_T * SCAN_I - 1) / (SCAN_T * SCAN_I);   // 98 <= 256
    scan_partial<<<nb, SCAN_T, 0, stream>>>(cnt, bsum, n);
    scan_bsums<<<1, 256, 0, stream>>>(bsum, nb);
    scan_final<<<nb, SCAN_T, 0, stream>>>(cnt, bsum, rowptr, n);
    scatter_kernel<<<eb, 256, 0, stream>>>(row, col, ew, deg, rowptr, fill, col_s, norm_s, e);

    // conv1: P1 = prop(x); h = relu(combine) + BN stats
    prop_kernel<NF><<<(n + 3) / 4, 256, 0, stream>>>(x, NF, rowptr, cnt, col_s, norm_s, U, n);
    combine1_kernel<<<768, 512, 0, stream>>>(x, U, rowptr, cnt, col_s, norm_s, W1, b1, H, stats, n);
    bn_finalize_kernel<<<1, 64, 0, stream>>>(stats, gamma, beta, 1.f / (float)n);
    bn_apply_kernel<<<2048, 256, 0, stream>>>(H, stats, n * C1 / 4);

    // conv2 + final linear: Q1 = prop(h_bn); out = fused combine
    prop_kernel<C1><<<(n + 3) / 4, 256, 0, stream>>>(H, C1, rowptr, cnt, col_s, norm_s, U, n);
    combine2_kernel<<<512, 512, 0, stream>>>(H, U, rowptr, cnt, col_s, norm_s, W2, b2, linW, linb, out, n);
}

// Round 3
// 814.628 us; speedup vs baseline: 1.7220x; 1.7220x over previous
//
#include <hip/hip_runtime.h>
#include <hip/hip_bf16.h>

static constexpr int NF   = 50;   // input features
static constexpr int C1   = 64;   // conv1/conv2 channels
static constexpr int OUTF = 16;   // final output features
static constexpr int SCAN_T = 256;
static constexpr int SCAN_I = 4;

// ---------------------------------------------------------------- CSR build
__global__ void deg_count_kernel(const int* __restrict__ row, const float* __restrict__ w,
                                 float* __restrict__ deg, int* __restrict__ cnt, int e)
{
    int i = blockIdx.x * blockDim.x + threadIdx.x;
    if (i < e) {
        int r = row[i];
        atomicAdd(&deg[r], w[i]);
        atomicAdd(&cnt[r], 1);
    }
}

__global__ void dis_kernel(float* __restrict__ deg, int n)
{
    int i = blockIdx.x * blockDim.x + threadIdx.x;
    if (i < n) {
        float d = deg[i];
        deg[i] = (d > 0.f) ? (1.f / sqrtf(d)) : 0.f;   // deg buffer becomes dis
    }
}

__global__ void scan_partial(const int* __restrict__ cnt, int* __restrict__ bsum, int n)
{
    __shared__ int sm[SCAN_T];
    int t = threadIdx.x;
    int base = blockIdx.x * SCAN_T * SCAN_I + t * SCAN_I;
    int s = 0;
    #pragma unroll
    for (int k = 0; k < SCAN_I; ++k) { int i = base + k; if (i < n) s += cnt[i]; }
    sm[t] = s; __syncthreads();
    for (int off = SCAN_T / 2; off > 0; off >>= 1) {
        if (t < off) sm[t] += sm[t + off];
        __syncthreads();
    }
    if (t == 0) bsum[blockIdx.x] = sm[0];
}

// single block; requires nb <= 256 (here nb = 98)
__global__ void scan_bsums(int* __restrict__ bsum, int nb)
{
    __shared__ int sm[256];
    int t = threadIdx.x;
    sm[t] = (t < nb) ? bsum[t] : 0;
    __syncthreads();
    for (int off = 1; off < 256; off <<= 1) {
        int v = (t >= off) ? sm[t - off] : 0;
        __syncthreads();
        sm[t] += v;
        __syncthreads();
    }
    if (t < nb) bsum[t] = (t == 0) ? 0 : sm[t - 1];   // exclusive
}

__global__ void scan_final(const int* __restrict__ cnt, const int* __restrict__ bsum,
                           int* __restrict__ rowptr, int n)
{
    __shared__ int sm[SCAN_T];
    int t = threadIdx.x;
    int base = blockIdx.x * SCAN_T * SCAN_I + t * SCAN_I;
    int v[SCAN_I]; int s = 0;
    #pragma unroll
    for (int k = 0; k < SCAN_I; ++k) { int i = base + k; v[k] = (i < n) ? cnt[i] : 0; s += v[k]; }
    sm[t] = s; __syncthreads();
    for (int off = 1; off < SCAN_T; off <<= 1) {
        int x = (t >= off) ? sm[t - off] : 0;
        __syncthreads();
        sm[t] += x;
        __syncthreads();
    }
    int pref = bsum[blockIdx.x] + sm[t] - s;   // thread-exclusive prefix
    #pragma unroll
    for (int k = 0; k < SCAN_I; ++k) {
        int i = base + k;
        if (i < n) { rowptr[i] = pref; pref += v[k]; }
    }
}

__global__ void scatter_kernel(const int* __restrict__ row, const int* __restrict__ col,
                               const float* __restrict__ w, const float* __restrict__ dis,
                               const int* __restrict__ rowptr, int* __restrict__ fill,
                               int* __restrict__ col_s, float* __restrict__ norm_s, int e)
{
    int i = blockIdx.x * blockDim.x + threadIdx.x;
    if (i < e) {
        int r = row[i], c = col[i];
        int pos = rowptr[r] + atomicAdd(&fill[r], 1);
        col_s[pos]  = c;
        norm_s[pos] = -dis[r] * w[i] * dis[c];
    }
}

// ---------------------------------------------------------------- propagate
// one wave per row; lane = feature; gather-only, no atomics.
// unroll-4 with independent accumulators -> 4 gathers in flight per wave.
template<int F>
__global__ void prop_kernel(const float* __restrict__ xin, int xstride,
                            const int* __restrict__ rowptr, const int* __restrict__ cnt,
                            const int* __restrict__ col_s, const float* __restrict__ norm_s,
                            float* __restrict__ yout, int n)
{
    int gw = (blockIdx.x * blockDim.x + threadIdx.x) >> 6;
    int lane = threadIdx.x & 63;
    if (gw >= n) return;
    int st = __builtin_amdgcn_readfirstlane(rowptr[gw]);
    int m  = __builtin_amdgcn_readfirstlane(cnt[gw]);
    // dead lanes (F=50: lanes 50..63) read feature 0 to stay in-bounds; result masked at write
    const int xi = (F == C1) ? lane : ((lane < F) ? lane : 0);
    float a0 = 0.f, a1 = 0.f, a2 = 0.f, a3 = 0.f;
    int t = 0;
    for (; t + 4 <= m; t += 4) {
        int   c0 = col_s[st + t],     c1 = col_s[st + t + 1];
        int   c2 = col_s[st + t + 2], c3 = col_s[st + t + 3];
        float n0 = norm_s[st + t],     n1 = norm_s[st + t + 1];
        float n2 = norm_s[st + t + 2], n3 = norm_s[st + t + 3];
        float g0 = xin[c0 * xstride + xi];
        float g1 = xin[c1 * xstride + xi];
        float g2 = xin[c2 * xstride + xi];
        float g3 = xin[c3 * xstride + xi];
        a0 += n0 * g0; a1 += n1 * g1; a2 += n2 * g2; a3 += n3 * g3;
    }
    for (; t < m; ++t)
        a0 += norm_s[st + t] * xin[col_s[st + t] * xstride + xi];
    float acc = (a0 + a1) + (a2 + a3);
    if (F == C1 || lane < F) yout[gw * C1 + lane] = acc;
}

// shared helper: unroll-4 gather of one CSR row from a stride-64 table
__device__ __forceinline__ float gather_row(const float* __restrict__ tab,
                                            const int* __restrict__ col_s,
                                            const float* __restrict__ norm_s,
                                            int st, int m, int lane)
{
    float a0 = 0.f, a1 = 0.f, a2 = 0.f, a3 = 0.f;
    int t = 0;
    for (; t + 4 <= m; t += 4) {
        int   c0 = col_s[st + t],     c1 = col_s[st + t + 1];
        int   c2 = col_s[st + t + 2], c3 = col_s[st + t + 3];
        float n0 = norm_s[st + t],     n1 = norm_s[st + t + 1];
        float n2 = norm_s[st + t + 2], n3 = norm_s[st + t + 3];
        float g0 = tab[c0 * C1 + lane];
        float g1 = tab[c1 * C1 + lane];
        float g2 = tab[c2 * C1 + lane];
        float g3 = tab[c3 * C1 + lane];
        a0 += n0 * g0; a1 += n1 * g1; a2 += n2 * g2; a3 += n3 * g3;
    }
    for (; t < m; ++t)
        a0 += norm_s[st + t] * tab[col_s[st + t] * C1 + lane];
    return (a0 + a1) + (a2 + a3);
}

// ---------------------------------------------------------------- conv1 combine (+BN stats)
// h = relu(x@W0 + P1@W1 + (2*prop(P1) - x)@W2 + b1); prop(P1) computed inline.
__global__ __launch_bounds__(512) void combine1_kernel(
    const float* __restrict__ x, const float* __restrict__ P1,
    const int* __restrict__ rowptr, const int* __restrict__ cnt,
    const int* __restrict__ col_s, const float* __restrict__ norm_s,
    const float* __restrict__ W1, const float* __restrict__ b1,
    float* __restrict__ h, float* __restrict__ stats, int n)
{
    __shared__ float WL[3 * NF * C1];     // 38400 B
    __shared__ float red[2][8][64];       // 4 KB
    for (int i = threadIdx.x; i < 3 * NF * C1; i += blockDim.x) WL[i] = W1[i];
    __syncthreads();

    const int lane = threadIdx.x & 63;
    const int wv   = threadIdx.x >> 6;
    const int gw   = blockIdx.x * 8 + wv;
    const int rstep = gridDim.x * 8 * 4;
    const float bias = b1[lane];
    float ssum = 0.f, ssq = 0.f;

    for (int r0 = gw * 4; r0 < n; r0 += rstep) {
        const int nr = min(4, n - r0);
        // inline prop(P1): lane = feature (lanes >= 50 compute garbage, never used)
        float s[4] = {0.f, 0.f, 0.f, 0.f};
        #pragma unroll
        for (int r = 0; r < 4; ++r) {
            if (r < nr) {
                int st = __builtin_amdgcn_readfirstlane(rowptr[r0 + r]);
                int m  = __builtin_amdgcn_readfirstlane(cnt[r0 + r]);
                s[r] = gather_row(P1, col_s, norm_s, st, m, lane);
            }
        }
        int rr[4];
        #pragma unroll
        for (int r = 0; r < 4; ++r) rr[r] = (r < nr) ? (r0 + r) : r0;   // clamp for safe loads

        float acc[4] = {bias, bias, bias, bias};
        for (int f = 0; f < NF; ++f) {
            float w0 = WL[f * C1 + lane];
            float w1 = WL[(NF + f) * C1 + lane];
            float w2 = WL[(2 * NF + f) * C1 + lane];
            #pragma unroll
            for (int r = 0; r < 4; ++r) {
                float t0 = x[rr[r] * NF + f];          // wave-broadcast load
                float t1 = P1[rr[r] * C1 + f];
                float t2 = 2.f * __shfl(s[r], f) - t0;
                acc[r] += t0 * w0 + t1 * w1 + t2 * w2;
            }
        }
        #pragma unroll
        for (int r = 0; r < 4; ++r) {
            if (r < nr) {
                float v = fmaxf(acc[r], 0.f);
                h[(r0 + r) * C1 + lane] = v;
                ssum += v; ssq += v * v;
            }
        }
    }
    red[0][wv][lane] = ssum;
    red[1][wv][lane] = ssq;
    __syncthreads();
    int t = threadIdx.x;
    if (t < 128) {
        int which = t >> 6, j = t & 63;
        float tot = 0.f;
        #pragma unroll
        for (int wq = 0; wq < 8; ++wq) tot += red[which][wq][j];
        atomicAdd(&stats[which * 64 + j], tot);
    }
}

// ---------------------------------------------------------------- batch norm
__global__ void bn_finalize_kernel(float* __restrict__ stats, const float* __restrict__ gamma,
                                   const float* __restrict__ beta, float inv_n)
{
    int j = threadIdx.x;
    if (j < 64) {
        float mu   = stats[j] * inv_n;
        float var  = stats[64 + j] * inv_n - mu * mu;
        float rstd = 1.f / sqrtf(var + 1e-5f);
        float sc   = gamma[j] * rstd;
        stats[128 + j] = sc;
        stats[192 + j] = beta[j] - mu * sc;
    }
}

__global__ void bn_apply_kernel(float* __restrict__ h, const float* __restrict__ stats, int n4)
{
    int i = blockIdx.x * blockDim.x + threadIdx.x;
    const int stride = gridDim.x * blockDim.x;      // multiple of 16 -> j0 invariant
    int j0 = (i * 4) & 63;
    float s0 = stats[128 + j0], s1 = stats[129 + j0], s2 = stats[130 + j0], s3 = stats[131 + j0];
    float b0 = stats[192 + j0], b1 = stats[193 + j0], b2 = stats[194 + j0], b3 = stats[195 + j0];
    float4* h4 = (float4*)h;
    for (; i < n4; i += stride) {
        float4 v = h4[i];
        v.x = v.x * s0 + b0;
        v.y = v.y * s1 + b1;
        v.z = v.z * s2 + b2;
        v.w = v.w * s3 + b3;
        h4[i] = v;
    }
}

// ---------------------------------------------------------------- conv2 combine + final linear
// g = relu(hb@W0 + Q1@W1 + (2*prop(Q1) - hb)@W2 + b2);  out = g @ linW^T + linb
__global__ __launch_bounds__(512) void combine2_kernel(
    const float* __restrict__ hb, const float* __restrict__ Q1,
    const int* __restrict__ rowptr, const int* __restrict__ cnt,
    const int* __restrict__ col_s, const float* __restrict__ norm_s,
    const float* __restrict__ W2, const float* __restrict__ b2,
    const float* __restrict__ linW, const float* __restrict__ linb,
    float* __restrict__ out, int n)
{
    __shared__ float WL[3 * C1 * C1];     // 48 KB
    __shared__ float LWT[C1 * OUTF];      // linW transposed [j][o], 4 KB
    __shared__ float gbuf[8][4][C1];      // 8 KB, per-wave staging for final linear
    for (int i = threadIdx.x; i < 3 * C1 * C1; i += blockDim.x) WL[i] = W2[i];
    for (int i = threadIdx.x; i < C1 * OUTF; i += blockDim.x) {
        int j = i / OUTF, o = i % OUTF;
        LWT[i] = linW[o * C1 + j];
    }
    __syncthreads();

    const int lane = threadIdx.x & 63;
    const int wv   = threadIdx.x >> 6;
    const int gw   = blockIdx.x * 8 + wv;
    const int rstep = gridDim.x * 8 * 4;
    const float bias = b2[lane];
    const float lb   = linb[lane & 15];
    const int rsel = lane >> 4, osel = lane & 15;

    for (int r0 = gw * 4; r0 < n; r0 += rstep) {
        const int nr = min(4, n - r0);
        float s[4] = {0.f, 0.f, 0.f, 0.f};
        #pragma unroll
        for (int r = 0; r < 4; ++r) {
            if (r < nr) {
                int st = __builtin_amdgcn_readfirstlane(rowptr[r0 + r]);
                int m  = __builtin_amdgcn_readfirstlane(cnt[r0 + r]);
                s[r] = gather_row(Q1, col_s, norm_s, st, m, lane);
            }
        }
        int rr[4];
        #pragma unroll
        for (int r = 0; r < 4; ++r) rr[r] = (r < nr) ? (r0 + r) : r0;

        float acc[4] = {bias, bias, bias, bias};
        for (int f = 0; f < C1; ++f) {
            float w0 = WL[f * C1 + lane];
            float w1 = WL[(C1 + f) * C1 + lane];
            float w2 = WL[(2 * C1 + f) * C1 + lane];
            #pragma unroll
            for (int r = 0; r < 4; ++r) {
                float t0 = hb[rr[r] * C1 + f];
                float t1 = Q1[rr[r] * C1 + f];
                float t2 = 2.f * __shfl(s[r], f) - t0;
                acc[r] += t0 * w0 + t1 * w1 + t2 * w2;
            }
        }
        // stage relu'd g for this wave's 4 rows, then 64 lanes cover 4 rows x 16 outs
        #pragma unroll
        for (int r = 0; r < 4; ++r)
            gbuf[wv][r][lane] = (r < nr) ? fmaxf(acc[r], 0.f) : 0.f;
        // same-wave LDS write->read: DS pipe is in-order per wave on CDNA
        float oa = lb;
        for (int j = 0; j < C1; ++j)
            oa += gbuf[wv][rsel][j] * LWT[j * OUTF + osel];
        int rw = r0 + rsel;
        if (rw < n) out[rw * OUTF + osel] = oa;   // contiguous 256B store per wave
    }
}

// ---------------------------------------------------------------- launch
extern "C" void kernel_launch(void* const* d_in, const int* in_sizes, int n_in,
                              void* d_out, int out_size, void* d_ws, size_t ws_size,
                              hipStream_t stream)
{
    const float* x     = (const float*)d_in[0];
    const int*   ei    = (const int*)  d_in[1];
    const float* ew    = (const float*)d_in[2];
    const float* W1    = (const float*)d_in[3];
    const float* b1    = (const float*)d_in[4];
    const float* W2    = (const float*)d_in[5];
    const float* b2    = (const float*)d_in[6];
    const float* gamma = (const float*)d_in[7];
    const float* beta  = (const float*)d_in[8];
    const float* linW  = (const float*)d_in[9];
    const float* linb  = (const float*)d_in[10];
    float* out = (float*)d_out;
    (void)n_in; (void)out_size; (void)ws_size;

    const int n = in_sizes[0] / NF;    // 100000
    const int e = in_sizes[2];         // 1600000
    const int* row = ei;
    const int* col = ei + e;

    char* ws = (char*)d_ws;
    size_t off = 0;
    auto alloc = [&](size_t bytes) -> void* {
        void* p = ws + off;
        off += (bytes + 255) & ~(size_t)255;
        return p;
    };
    float* deg    = (float*)alloc((size_t)n * 4);   // becomes dis in-place
    int*   cnt    = (int*)  alloc((size_t)n * 4);
    int*   rowptr = (int*)  alloc((size_t)n * 4);
    int*   fill   = (int*)  alloc((size_t)n * 4);
    int*   bsum   = (int*)  alloc(256 * 4);
    float* stats  = (float*)alloc(256 * 4);         // [sum|sumsq|scale|shift] x 64
    int*   col_s  = (int*)  alloc((size_t)e * 4);
    float* norm_s = (float*)alloc((size_t)e * 4);
    float* U      = (float*)alloc((size_t)n * C1 * 4);   // P1, then Q1
    float* H      = (float*)alloc((size_t)n * C1 * 4);   // h, BN in-place

    hipMemsetAsync(deg,   0, (size_t)n * 4, stream);
    hipMemsetAsync(cnt,   0, (size_t)n * 4, stream);
    hipMemsetAsync(fill,  0, (size_t)n * 4, stream);
    hipMemsetAsync(stats, 0, 256 * 4, stream);

    const int eb  = (e + 255) / 256;
    const int nbk = (n + 255) / 256;
    deg_count_kernel<<<eb, 256, 0, stream>>>(row, ew, deg, cnt, e);
    dis_kernel<<<nbk, 256, 0, stream>>>(deg, n);

    const int nb = (n + SCAN_T * SCAN_I - 1) / (SCAN_T * SCAN_I);   // 98 <= 256
    scan_partial<<<nb, SCAN_T, 0, stream>>>(cnt, bsum, n);
    scan_bsums<<<1, 256, 0, stream>>>(bsum, nb);
    scan_final<<<nb, SCAN_T, 0, stream>>>(cnt, bsum, rowptr, n);
    scatter_kernel<<<eb, 256, 0, stream>>>(row, col, ew, deg, rowptr, fill, col_s, norm_s, e);

    // conv1: P1 = prop(x); h = relu(combine) + BN stats
    prop_kernel<NF><<<(n + 3) / 4, 256, 0, stream>>>(x, NF, rowptr, cnt, col_s, norm_s, U, n);
    combine1_kernel<<<768, 512, 0, stream>>>(x, U, rowptr, cnt, col_s, norm_s, W1, b1, H, stats, n);
    bn_finalize_kernel<<<1, 64, 0, stream>>>(stats, gamma, beta, 1.f / (float)n);
    bn_apply_kernel<<<2048, 256, 0, stream>>>(H, stats, n * C1 / 4);

    // conv2 + final linear: Q1 = prop(h_bn); out = fused combine
    prop_kernel<C1><<<(n + 3) / 4, 256, 0, stream>>>(H, C1, rowptr, cnt, col_s, norm_s, U, n);
    combine2_kernel<<<512, 512, 0, stream>>>(H, U, rowptr, cnt, col_s, norm_s, W2, b2, linW, linb, out, n);
}